// Round 6
// baseline (123.003 us; speedup 1.0000x reference)
//
#include <hip/hip_runtime.h>
#include <math.h>

#define BB 64
#define TT 2048
#define HIDD 256
#define FASTN 64
#define SLOWN 256
#define VOC 64
#define TLOOP (TT - 3)   // 2045 scan steps
#define NEGC -1000000000.0f
#define EPAD 257         // padded emb row stride (bank-conflict-free)

// ---------------------------------------------------------------------------
// K1 (batch-independent tables, 257 blocks x 256):
//  blocks 0..255: qTok[u][jt*64+j] = emb[u] @ Wq[:, jt*64+j] + bq  (u=blk>>2)
//  block 256    : act/dem -> prS[v] = act ? rank(dem_v) : 0xFF ; invS[r] = v
// ---------------------------------------------------------------------------
__global__ __launch_bounds__(256) void k_tab(
    const float* __restrict__ emb,
    const float* __restrict__ Wg, const float* __restrict__ bg,
    const float* __restrict__ Wd, const float* __restrict__ bd,
    const float* __restrict__ Wq, const float* __restrict__ bq,
    float* __restrict__ qTok, int* __restrict__ prG, int* __restrict__ invG) {
  const int tid = threadIdx.x;
  __shared__ float eS[HIDD];
  __shared__ float part[4][64];
  __shared__ float demS[64];

  if (blockIdx.x < 256) {
    const int u = blockIdx.x >> 2, jt = blockIdx.x & 3;
    eS[tid] = emb[u * HIDD + tid];
    __syncthreads();
    const int j = tid & 63, kp = tid >> 6;
    const float* w = &Wq[(kp * 64) * HIDD + jt * 64 + j];
    const float* e = &eS[kp * 64];
    float acc = 0.f;
#pragma unroll 8
    for (int kk = 0; kk < 64; ++kk) acc += e[kk] * w[kk * HIDD];
    part[kp][j] = acc;
    __syncthreads();
    if (tid < 64)
      qTok[u * HIDD + jt * 64 + tid] =
          part[0][tid] + part[1][tid] + part[2][tid] + part[3][tid] + bq[jt * 64 + tid];
  } else {
    // gate + demotion dots: thread = (v, kpart)
    const int v = tid & 63, kp = tid >> 6;
    const float* e = &emb[v * HIDD + kp * 64];
    const float* wg = &Wg[kp * 64];
    const float* wd = &Wd[kp * 64];
    float g = 0.f, d = 0.f;
#pragma unroll 8
    for (int k = 0; k < 64; ++k) { float ev = e[k]; g += ev * wg[k]; d += ev * wd[k]; }
    part[kp][v] = g;
    __syncthreads();
    __shared__ float dpart[4][64];
    dpart[kp][v] = d;
    __syncthreads();
    int myact = 0;
    if (tid < 64) {
      float gg = part[0][tid] + part[1][tid] + part[2][tid] + part[3][tid] + bg[0];
      float dd = dpart[0][tid] + dpart[1][tid] + dpart[2][tid] + dpart[3][tid] + bd[0];
      myact = (1.f / (1.f + expf(-gg)) >= 0.4f) ? 1 : 0;
      demS[tid] = dd;
    }
    __syncthreads();
    if (tid < 64) {
      float dv = demS[tid];
      int r = 0;
      for (int u2 = 0; u2 < 64; ++u2) {
        float du = demS[u2];
        r += (du < dv || (du == dv && u2 < tid)) ? 1 : 0;
      }
      prG[tid] = myact ? r : 0xFF;
      invG[r] = tid;
    }
  }
}

// ---------------------------------------------------------------------------
// K2 (per-batch, 64 blocks x 256): pack -> wave0 Lindley scan -> epilogue.
// Scan: lane k: a <- max(a,1) + ([z<=k]-1)  (== evict-min + insert);
// e += [a>0] over last min(n,256) LRU steps gives the slow-ring counts.
// Token counts = adjacent lane diffs; slot permutation is output-invariant.
// ---------------------------------------------------------------------------
__global__ __launch_bounds__(256) void k_main(
    const int* __restrict__ seq, const float* __restrict__ emb,
    const float* __restrict__ qTok, const int* __restrict__ prG,
    const int* __restrict__ invG,
    const float* __restrict__ Wo, const float* __restrict__ bo,
    float* __restrict__ out) {
  const int b = blockIdx.x;
  const int tid = threadIdx.x;
  const int lane = tid & 63;

  __shared__ float embS[VOC * EPAD];                    // 65792 B
  __shared__ float WoS[HIDD * VOC];                     // 65536 B
  __shared__ __align__(16) unsigned char toksB[TT];     // 2048 B
  __shared__ __align__(16) unsigned char zsB[TT + 32];  // 2080 B
  __shared__ float qLastS[HIDD], ctxS[HIDD];
  __shared__ float pp[4][64];
  __shared__ float wS[64];
  __shared__ int prS[64], invS[64], cntTok[64];
  __shared__ int usedSh, susedSh;

  // ---- entry: seq into registers; tables; qTok[lastv]; emb+Wo staging ----
  const int4* seq4 = (const int4*)(seq + b * TT);
  const int4 sq0 = seq4[tid];
  const int4 sq1 = seq4[tid + 256];
  const int lastv = seq[b * TT + TT - 1];

  if (tid < 64) { prS[tid] = prG[tid]; invS[tid] = invG[tid]; }
  qLastS[tid] = qTok[lastv * HIDD + tid];

  const float4* emb4 = (const float4*)emb;
  for (int i = tid; i < VOC * 64; i += 256) {
    float4 e = emb4[i];
    float* d = &embS[(i >> 6) * EPAD + ((i & 63) << 2)];
    d[0] = e.x; d[1] = e.y; d[2] = e.z; d[3] = e.w;
  }
  {
    const float4* Wo4 = (const float4*)Wo;
    float4* WoS4 = (float4*)WoS;
    for (int i = tid; i < HIDD * VOC / 4; i += 256) WoS4[i] = Wo4[i];
  }
  __syncthreads();

  // ---- pack rank stream from registers (0xFF = skip) ----
  {
    int t0 = tid * 4;
    int ta[4] = {sq0.x, sq0.y, sq0.z, sq0.w};
    int tb[4] = {sq1.x, sq1.y, sq1.z, sq1.w};
    unsigned u0 = 0, u1 = 0;
#pragma unroll
    for (int j = 0; j < 4; ++j) {
      unsigned byA = (t0 + j < TLOOP) ? (unsigned)prS[ta[j]] : 0xFFu;
      unsigned byB = (1024 + t0 + j < TLOOP) ? (unsigned)prS[tb[j]] : 0xFFu;
      u0 |= byA << (8 * j);
      u1 |= byB << (8 * j);
    }
    ((unsigned*)toksB)[tid] = u0;
    ((unsigned*)toksB)[tid + 256] = u1;
  }
  __syncthreads();

  // ---- wave0: compact + Lindley scan ----
  if (tid < 64) {
    const uint4 wA = *((const uint4*)(toksB + lane * 32));
    const uint4 wB = *((const uint4*)(toksB + lane * 32 + 16));
    unsigned int dw[8] = {wA.x, wA.y, wA.z, wA.w, wB.x, wB.y, wB.z, wB.w};
    int c = 0;
#pragma unroll
    for (int d = 0; d < 8; ++d)
#pragma unroll
      for (int j = 0; j < 4; ++j)
        c += (((dw[d] >> (8 * j)) & 0xFFu) != 0xFFu) ? 1 : 0;
    int incl = c;
    for (int s = 1; s < 64; s <<= 1) {
      int t = __shfl_up(incl, s);
      if (lane >= s) incl += t;
    }
    int pos = incl - c;
#pragma unroll
    for (int d = 0; d < 8; ++d)
#pragma unroll
      for (int j = 0; j < 4; ++j) {
        unsigned int z = (dw[d] >> (8 * j)) & 0xFFu;
        if (z != 0xFFu) zsB[pos++] = (unsigned char)z;
      }
    const int A = __builtin_amdgcn_readfirstlane(__shfl(incl, 63));

    const int fillN = A < 64 ? A : 64;
    const int n = A - fillN;
    const int win = n < 256 ? n : 256;
    const int wstart = A - win;

    int a = 0, e = 0;
    const uint4* zs4 = (const uint4*)zsB;

    if (A >= 64) {
#pragma unroll
      for (int g = 0; g < 4; ++g) {
        uint4 q4 = zs4[g];
        unsigned int ds[4] = {q4.x, q4.y, q4.z, q4.w};
#pragma unroll
        for (int d = 0; d < 4; ++d)
#pragma unroll
          for (int j = 0; j < 4; ++j) {
            int z = (int)((ds[d] >> (8 * j)) & 0xFFu);
            a += (z <= lane) ? 1 : 0;
          }
      }
      uint4 cur = zs4[4];
      for (int g = 4; g * 16 < A; ++g) {
        uint4 nxt = zs4[g + 1];  // +32 pad; overrun bytes never used
        const int gs = g * 16;
        unsigned int ds[4] = {cur.x, cur.y, cur.z, cur.w};
        if (gs + 16 <= wstart) {                     // MAIN
#pragma unroll
          for (int d = 0; d < 4; ++d)
#pragma unroll
            for (int j = 0; j < 4; ++j) {
              int z = (int)((ds[d] >> (8 * j)) & 0xFFu);
              int xm1 = (z <= lane) ? 0 : -1;
              a = max(a, 1) + xm1;
            }
        } else if (gs >= wstart && gs + 16 <= A) {   // WIN
#pragma unroll
          for (int d = 0; d < 4; ++d)
#pragma unroll
            for (int j = 0; j < 4; ++j) {
              int z = (int)((ds[d] >> (8 * j)) & 0xFFu);
              int xm1 = (z <= lane) ? 0 : -1;
              e += (a > 0) ? 1 : 0;
              a = max(a, 1) + xm1;
            }
        } else {                                     // GATED boundary
#pragma unroll
          for (int d = 0; d < 4; ++d)
#pragma unroll
            for (int j = 0; j < 4; ++j) {
              int i = gs + d * 4 + j;
              int z = (int)((ds[d] >> (8 * j)) & 0xFFu);
              int xm1 = (z <= lane) ? 0 : -1;
              bool vld = i < A;
              bool cg = (i >= wstart) && vld;
              e += (cg && a > 0) ? 1 : 0;
              int an = max(a, 1) + xm1;
              a = vld ? an : a;
            }
        }
        cur = nxt;
      }
    } else {
      for (int i = 0; i < A; ++i) {
        int z = zsB[i];
        a += (z <= lane) ? 1 : 0;
      }
    }

    int ap = __shfl_up(a, 1); if (lane == 0) ap = 0;
    int ep = __shfl_up(e, 1); if (lane == 0) ep = 0;
    cntTok[invS[lane]] = (a - ap) + (e - ep);
    if (lane == 0) { usedSh = fillN + win; susedSh = win; }
  }
  __syncthreads();

  // ---- scores sc[v] = emb[v].qLast ; softmax regroup over counts ----
  {
    int v = tid & 63, part = tid >> 6;
    const float* er = &embS[v * EPAD + part * 64];
    const float* qr = &qLastS[part * 64];
    float s = 0.f;
#pragma unroll 8
    for (int k = 0; k < 64; ++k) s += er[k] * qr[k];
    pp[part][v] = s;
  }
  __syncthreads();
  if (tid < 64) {
    float sc = pp[0][tid] + pp[1][tid] + pp[2][tid] + pp[3][tid];
    int c = cntTok[tid];
    float m = (c > 0) ? sc : NEGC;
    for (int off = 32; off; off >>= 1) m = fmaxf(m, __shfl_xor(m, off));
    float w = (c > 0) ? (float)c * expf(sc - m) : 0.f;
    float z = w;
    for (int off = 32; off; off >>= 1) z += __shfl_xor(z, off);
    z += (float)(FASTN + SLOWN - usedSh) * expf(NEGC - m);  // 0 unless empty
    wS[tid] = w / z;
  }
  __syncthreads();

  // ---- ctx[h] = sum_u wS[u] * emb[u][h] ----
  {
    float cacc = 0.f;
#pragma unroll 8
    for (int u = 0; u < 64; ++u) cacc += wS[u] * embS[u * EPAD + tid];
    ctxS[tid] = cacc;
  }
  __syncthreads();

  // ---- logits = ctx @ Wo + bo ----
  {
    int o = tid & 63, part = tid >> 6;
    const float* cr = &ctxS[part * 64];
    const float* wr = &WoS[part * 64 * VOC + o];
    float s = 0.f;
#pragma unroll 8
    for (int k = 0; k < 64; ++k) s += cr[k] * wr[k * VOC];
    pp[part][o] = s;
  }
  __syncthreads();
  if (tid < 64)
    out[b * VOC + tid] = pp[0][tid] + pp[1][tid] + pp[2][tid] + pp[3][tid] + bo[tid];
  out[BB * VOC + b * SLOWN + tid] = (tid < susedSh) ? 1.0f : 0.0f;
}

// ---------------------------------------------------------------------------
extern "C" void kernel_launch(void* const* d_in, const int* in_sizes, int n_in,
                              void* d_out, int out_size, void* d_ws, size_t ws_size,
                              hipStream_t stream) {
  const int*   seq = (const int*)d_in[0];
  const float* emb = (const float*)d_in[1];
  const float* Wg  = (const float*)d_in[2];
  const float* bg  = (const float*)d_in[3];
  const float* Wd  = (const float*)d_in[4];
  const float* bd  = (const float*)d_in[5];
  const float* Wq  = (const float*)d_in[6];
  const float* bq  = (const float*)d_in[7];
  const float* Wo  = (const float*)d_in[8];
  const float* bo  = (const float*)d_in[9];
  float* out = (float*)d_out;

  char* ws = (char*)d_ws;
  float* qTok = (float*)ws;                    // 64*256 floats
  int*   prG  = (int*)(ws + 16384 * 4);        // 64
  int*   invG = (int*)(ws + 16448 * 4);        // 64

  k_tab<<<dim3(257), dim3(256), 0, stream>>>(emb, Wg, bg, Wd, bd, Wq, bq,
                                             qTok, prG, invG);
  k_main<<<dim3(64), dim3(256), 0, stream>>>(seq, emb, qTok, prG, invG,
                                             Wo, bo, out);
}

// Round 7
// 94.902 us; speedup vs baseline: 1.2961x; 1.2961x over previous
//
#include <hip/hip_runtime.h>
#include <math.h>

#define BB 64
#define TT 2048
#define HIDD 256
#define FASTN 64
#define SLOWN 256
#define VOC 64
#define TLOOP (TT - 3)   // 2045 scan steps
#define NEGC -1000000000.0f
#define EPAD 257         // padded emb row stride (bank-conflict-free)
#define NEGBIG (-(1 << 20))
#define BYTEAT(U, J) ((int)(((U) >> (8 * (J))) & 0xFFu))

// ---------------------------------------------------------------------------
// K1 (batch-independent tables, 257 blocks x 256):
//  blocks 0..255: qTok[u][jt*64+j] = emb[u] @ Wq[:, jt*64+j] + bq
//  block 256    : prG[v] = act ? rank(dem_v) : 0xFF ; invG[r] = v
// ---------------------------------------------------------------------------
__global__ __launch_bounds__(256) void k_tab(
    const float* __restrict__ emb,
    const float* __restrict__ Wg, const float* __restrict__ bg,
    const float* __restrict__ Wd, const float* __restrict__ bd,
    const float* __restrict__ Wq, const float* __restrict__ bq,
    float* __restrict__ qTok, int* __restrict__ prG, int* __restrict__ invG) {
  const int tid = threadIdx.x;
  __shared__ float eS[HIDD];
  __shared__ float part[4][64];
  __shared__ float demS[64];

  if (blockIdx.x < 256) {
    const int u = blockIdx.x >> 2, jt = blockIdx.x & 3;
    eS[tid] = emb[u * HIDD + tid];
    __syncthreads();
    const int j = tid & 63, kp = tid >> 6;
    const float* w = &Wq[(kp * 64) * HIDD + jt * 64 + j];
    const float* e = &eS[kp * 64];
    float acc = 0.f;
#pragma unroll 8
    for (int kk = 0; kk < 64; ++kk) acc += e[kk] * w[kk * HIDD];
    part[kp][j] = acc;
    __syncthreads();
    if (tid < 64)
      qTok[u * HIDD + jt * 64 + tid] =
          part[0][tid] + part[1][tid] + part[2][tid] + part[3][tid] + bq[jt * 64 + tid];
  } else {
    const int v = tid & 63, kp = tid >> 6;
    const float* e = &emb[v * HIDD + kp * 64];
    const float* wg = &Wg[kp * 64];
    const float* wd = &Wd[kp * 64];
    float g = 0.f, d = 0.f;
#pragma unroll 8
    for (int k = 0; k < 64; ++k) { float ev = e[k]; g += ev * wg[k]; d += ev * wd[k]; }
    part[kp][v] = g;
    __syncthreads();
    __shared__ float dpart[4][64];
    dpart[kp][v] = d;
    __syncthreads();
    int myact = 0;
    if (tid < 64) {
      float gg = part[0][tid] + part[1][tid] + part[2][tid] + part[3][tid] + bg[0];
      float dd = dpart[0][tid] + dpart[1][tid] + dpart[2][tid] + dpart[3][tid] + bd[0];
      myact = (1.f / (1.f + expf(-gg)) >= 0.4f) ? 1 : 0;
      demS[tid] = dd;
    }
    __syncthreads();
    if (tid < 64) {
      float dv = demS[tid];
      int r = 0;
      for (int u2 = 0; u2 < 64; ++u2) {
        float du = demS[u2];
        r += (du < dv || (du == dv && u2 < tid)) ? 1 : 0;
      }
      prG[tid] = myact ? r : 0xFF;
      invG[r] = tid;
    }
  }
}

// ---------------------------------------------------------------------------
// K2 (per-batch, 64 blocks x 512 = 8 waves). Time-parallel Lindley scan:
// step f(a)=max(a+p,q): fill (p,q)=(x,-inf), LRU (p,q)=(x-1,x); maps compose
// associatively: segment -> (P,Q). Pass1: 8 segments in parallel compute
// (P,Q); combine gives each wave's entry a; pass2 re-runs segments in
// parallel for final a + windowed eviction counts e (slow FIFO ring of
// capacity 256 = last min(n,256) evictions). Counts = adjacent lane diffs.
// ---------------------------------------------------------------------------
__global__ __launch_bounds__(512) void k_main(
    const int* __restrict__ seq, const float* __restrict__ emb,
    const float* __restrict__ qTok, const int* __restrict__ prG,
    const int* __restrict__ invG,
    const float* __restrict__ Wo, const float* __restrict__ bo,
    float* __restrict__ out) {
  const int b = blockIdx.x;
  const int tid = threadIdx.x;
  const int lane = tid & 63;
  const int wv = tid >> 6;

  __shared__ float embS[VOC * EPAD];                    // 65792 B
  __shared__ float WoS[HIDD * VOC];                     // 65536 B
  __shared__ __align__(16) unsigned char zsB[2080];
  __shared__ float qLastS[HIDD], ctxS[HIDD];
  __shared__ float pp[4][64];
  __shared__ float wS[64];
  __shared__ int prS[64], invS[64], cntTok[64];
  __shared__ int CS[8];
  __shared__ int PsS[8][64], QsS[8][64], aEndS[8][64], eSS[8][64];

  // ---- entry: seq regs, tables, qTok[lastv], emb+Wo staging ----
  const int4 sq = ((const int4*)(seq + b * TT))[tid];   // tokens 4t..4t+3
  const int lastv = seq[b * TT + TT - 1];
  if (tid < 64) { prS[tid] = prG[tid]; invS[tid] = invG[tid]; }
  if (tid < 256) qLastS[tid] = qTok[lastv * HIDD + tid];
  const float4* emb4 = (const float4*)emb;
  for (int i = tid; i < VOC * 64; i += 512) {
    float4 e = emb4[i];
    float* d = &embS[(i >> 6) * EPAD + ((i & 63) << 2)];
    d[0] = e.x; d[1] = e.y; d[2] = e.z; d[3] = e.w;
  }
  {
    const float4* Wo4 = (const float4*)Wo;
    float4* WoS4 = (float4*)WoS;
    for (int i = tid; i < HIDD * VOC / 4; i += 512) WoS4[i] = Wo4[i];
  }
  __syncthreads();

  // ---- pack 4 tokens -> rank bytes in regs; wave-count actives ----
  const int t0 = tid * 4;
  int tk[4] = {sq.x, sq.y, sq.z, sq.w};
  int by[4]; int c = 0;
#pragma unroll
  for (int j = 0; j < 4; ++j) {
    int r = prS[tk[j]];
    by[j] = (t0 + j < TLOOP) ? r : 0xFF;
    c += (by[j] != 0xFF) ? 1 : 0;
  }
  int incl = c;
  for (int s = 1; s < 64; s <<= 1) {
    int t = __shfl_up(incl, s);
    if (lane >= s) incl += t;
  }
  if (lane == 63) CS[wv] = incl;
  __syncthreads();

  int Ow = 0, A = 0;
#pragma unroll
  for (int w2 = 0; w2 < 8; ++w2) {
    int cw = CS[w2];
    Ow += (w2 < wv) ? cw : 0;
    A += cw;
  }
  {
    int pos = Ow + incl - c;
#pragma unroll
    for (int j = 0; j < 4; ++j)
      if (by[j] != 0xFF) zsB[pos++] = (unsigned char)by[j];
  }
  __syncthreads();

  const int fsplit = A < 64 ? A : 64;
  const int nL = A - fsplit;
  const int win = nL < 256 ? nL : 256;
  const int wstart = A - win;
  const int L = (((A + 7) >> 3) + 15) & ~15;  // seg len, mult of 16
  const int baseW = wv * L;
  const int endW = min(baseW + L, A);

  // ---- pass 1: per-segment map (P,Q), lane = rank threshold ----
  int P = 0, Q = NEGBIG;
  for (int g = baseW; g < endW; g += 16) {
    uint4 t4 = *(const uint4*)(zsB + g);
    unsigned dsw[4] = {t4.x, t4.y, t4.z, t4.w};
    const int gHi = min(g + 16, endW);
    if (gHi == g + 16 && gHi <= fsplit) {            // FILL
#pragma unroll
      for (int d = 0; d < 4; ++d)
#pragma unroll
        for (int j = 0; j < 4; ++j) {
          int x = (BYTEAT(dsw[d], j) <= lane) ? 1 : 0;
          P += x; Q += x;
        }
    } else if (gHi == g + 16 && g >= fsplit) {       // LRU
#pragma unroll
      for (int d = 0; d < 4; ++d)
#pragma unroll
        for (int j = 0; j < 4; ++j) {
          int x = (BYTEAT(dsw[d], j) <= lane) ? 1 : 0;
          P += x - 1;
          Q = max(Q + x - 1, x);
        }
    } else {                                         // GATED
#pragma unroll
      for (int d = 0; d < 4; ++d)
#pragma unroll
        for (int j = 0; j < 4; ++j) {
          int i = g + d * 4 + j;
          int x = (BYTEAT(dsw[d], j) <= lane) ? 1 : 0;
          bool vld = i < endW;
          bool fil = i < fsplit;
          int p = fil ? x : x - 1;
          int q = fil ? NEGBIG : x;
          int Pn = P + p;
          int Qn = max(Q + p, q);
          P = vld ? Pn : P;
          Q = vld ? Qn : Q;
        }
    }
  }
  PsS[wv][lane] = P;
  QsS[wv][lane] = Q;
  __syncthreads();

  // ---- combine: entry value for my segment ----
  int a = 0;
  for (int w2 = 0; w2 < wv; ++w2)
    a = max(a + PsS[w2][lane], QsS[w2][lane]);

  // ---- pass 2: rerun segment for final a + windowed eviction count e ----
  int e = 0;
  for (int g = baseW; g < endW; g += 16) {
    uint4 t4 = *(const uint4*)(zsB + g);
    unsigned dsw[4] = {t4.x, t4.y, t4.z, t4.w};
    const int gHi = min(g + 16, endW);
    const bool full = (gHi == g + 16);
    if (full && gHi <= fsplit) {                     // FILL
#pragma unroll
      for (int d = 0; d < 4; ++d)
#pragma unroll
        for (int j = 0; j < 4; ++j)
          a += (BYTEAT(dsw[d], j) <= lane) ? 1 : 0;
    } else if (full && g >= fsplit && gHi <= wstart) {  // MAIN
#pragma unroll
      for (int d = 0; d < 4; ++d)
#pragma unroll
        for (int j = 0; j < 4; ++j) {
          int xm1 = (BYTEAT(dsw[d], j) <= lane) ? 0 : -1;
          a = max(a, 1) + xm1;
        }
    } else if (full && g >= wstart) {                // WIN
#pragma unroll
      for (int d = 0; d < 4; ++d)
#pragma unroll
        for (int j = 0; j < 4; ++j) {
          int xm1 = (BYTEAT(dsw[d], j) <= lane) ? 0 : -1;
          e += (a > 0) ? 1 : 0;
          a = max(a, 1) + xm1;
        }
    } else {                                         // GATED
#pragma unroll
      for (int d = 0; d < 4; ++d)
#pragma unroll
        for (int j = 0; j < 4; ++j) {
          int i = g + d * 4 + j;
          int x = (BYTEAT(dsw[d], j) <= lane) ? 1 : 0;
          bool vld = i < endW;
          bool fil = i < fsplit;
          bool wg = vld && (i >= wstart);
          e += (wg && a > 0) ? 1 : 0;
          int af = a + x;
          int al = max(a, 1) + (x - 1);
          int an = fil ? af : al;
          a = vld ? an : a;
        }
    }
  }
  aEndS[wv][lane] = a;
  eSS[wv][lane] = e;
  __syncthreads();

  // ---- finalize counts (one wave) ----
  if (tid < 64) {
    int af = aEndS[7][lane];
    int et = 0;
#pragma unroll
    for (int w2 = 0; w2 < 8; ++w2) et += eSS[w2][lane];
    int ap = __shfl_up(af, 1); if (lane == 0) ap = 0;
    int ep = __shfl_up(et, 1); if (lane == 0) ep = 0;
    cntTok[invS[lane]] = (af - ap) + (et - ep);
  }
  __syncthreads();

  // ---- scores sc[v] = emb[v].qLast ; softmax regroup over counts ----
  if (tid < 256) {
    int v = tid & 63, part = tid >> 6;
    const float* er = &embS[v * EPAD + part * 64];
    const float* qr = &qLastS[part * 64];
    float s = 0.f;
#pragma unroll 8
    for (int k = 0; k < 64; ++k) s += er[k] * qr[k];
    pp[part][v] = s;
  }
  __syncthreads();
  if (tid < 64) {
    float sc = pp[0][tid] + pp[1][tid] + pp[2][tid] + pp[3][tid];
    int cc = cntTok[tid];
    float m = (cc > 0) ? sc : NEGC;
    for (int off = 32; off; off >>= 1) m = fmaxf(m, __shfl_xor(m, off));
    float w = (cc > 0) ? (float)cc * expf(sc - m) : 0.f;
    float z = w;
    for (int off = 32; off; off >>= 1) z += __shfl_xor(z, off);
    z += (float)(FASTN + SLOWN - (fsplit + win)) * expf(NEGC - m);
    wS[tid] = w / z;
  }
  __syncthreads();

  // ---- ctx[h] = sum_u wS[u] * emb[u][h] ----
  if (tid < 256) {
    float cacc = 0.f;
#pragma unroll 8
    for (int u = 0; u < 64; ++u) cacc += wS[u] * embS[u * EPAD + tid];
    ctxS[tid] = cacc;
  }
  __syncthreads();

  // ---- logits = ctx @ Wo + bo ----
  if (tid < 256) {
    int o = tid & 63, part = tid >> 6;
    const float* cr = &ctxS[part * 64];
    const float* wr = &WoS[part * 64 * VOC + o];
    float s = 0.f;
#pragma unroll 8
    for (int k = 0; k < 64; ++k) s += cr[k] * wr[k * VOC];
    pp[part][o] = s;
  }
  __syncthreads();
  if (tid < 64)
    out[b * VOC + tid] = pp[0][tid] + pp[1][tid] + pp[2][tid] + pp[3][tid] + bo[tid];
  if (tid < 256)
    out[BB * VOC + b * SLOWN + tid] = (tid < win) ? 1.0f : 0.0f;
}

// ---------------------------------------------------------------------------
extern "C" void kernel_launch(void* const* d_in, const int* in_sizes, int n_in,
                              void* d_out, int out_size, void* d_ws, size_t ws_size,
                              hipStream_t stream) {
  const int*   seq = (const int*)d_in[0];
  const float* emb = (const float*)d_in[1];
  const float* Wg  = (const float*)d_in[2];
  const float* bg  = (const float*)d_in[3];
  const float* Wd  = (const float*)d_in[4];
  const float* bd  = (const float*)d_in[5];
  const float* Wq  = (const float*)d_in[6];
  const float* bq  = (const float*)d_in[7];
  const float* Wo  = (const float*)d_in[8];
  const float* bo  = (const float*)d_in[9];
  float* out = (float*)d_out;

  char* ws = (char*)d_ws;
  float* qTok = (float*)ws;                    // 64*256 floats
  int*   prG  = (int*)(ws + 16384 * 4);        // 64
  int*   invG = (int*)(ws + 16448 * 4);        // 64

  k_tab<<<dim3(257), dim3(256), 0, stream>>>(emb, Wg, bg, Wd, bd, Wq, bq,
                                             qTok, prG, invG);
  k_main<<<dim3(64), dim3(512), 0, stream>>>(seq, emb, qTok, prG, invG,
                                             Wo, bo, out);
}

// Round 8
// 94.706 us; speedup vs baseline: 1.2988x; 1.0021x over previous
//
#include <hip/hip_runtime.h>
#include <math.h>

#define BB 64
#define TT 2048
#define HIDD 256
#define FASTN 64
#define SLOWN 256
#define VOC 64
#define TLOOP (TT - 3)   // 2045 scan steps
#define NEGC -1000000000.0f
#define EPAD 257         // padded emb row stride (bank-conflict-free)
#define NEGBIG (-(1 << 20))
#define BYTEAT(U, J) ((int)(((U) >> (8 * (J))) & 0xFFu))

// ---------------------------------------------------------------------------
// Single fused kernel (64 blocks x 512 = 8 waves). Per block:
//  1. stage emb (padded) + Wo into LDS; seq into registers.
//  2. gate/dem dots -> act, dem; rank (ascending dem, tie by id) -> prS/invS.
//  3. pack rank stream (0xFF = inactive) -> compact to zsB via prefix sums.
//  4. time-parallel Lindley scan: step f(a)=max(a+p,q); fill (p,q)=(x,-inf),
//     LRU (p,q)=(x-1,x); maps compose associatively -> segment (P,Q).
//     Pass1: 8 segments' (P,Q) in parallel; combine -> per-wave entry a;
//     Pass2: rerun for final a + windowed eviction counts e (slow FIFO ring
//     = last min(n,256) evictions). Token counts = adjacent lane diffs.
//     (Slot permutation is output-invariant; counts determine the output.)
//  5. qLast = emb[lastv] @ Wq + bq (per-block GEMV, Wq L2-resident).
//  6. scores -> count-weighted softmax regroup -> ctx -> logits; slow_mask.
// ---------------------------------------------------------------------------
__global__ __launch_bounds__(512) void k_one(
    const int* __restrict__ seq, const float* __restrict__ emb,
    const float* __restrict__ Wg, const float* __restrict__ bg,
    const float* __restrict__ Wd, const float* __restrict__ bd,
    const float* __restrict__ Wq, const float* __restrict__ bq,
    const float* __restrict__ Wo, const float* __restrict__ bo,
    float* __restrict__ out) {
  const int b = blockIdx.x;
  const int tid = threadIdx.x;
  const int lane = tid & 63;
  const int wv = tid >> 6;

  __shared__ float embS[VOC * EPAD];                    // 65792 B
  __shared__ float WoS[HIDD * VOC];                     // 65536 B
  __shared__ __align__(16) unsigned char zsB[2080];
  __shared__ float qLastS[HIDD], ctxS[HIDD];
  __shared__ float pp[4][64];
  __shared__ float gp8[8][64], dp8[8][64];
  __shared__ float qp2[2][HIDD];
  __shared__ float demS[64], wS[64];
  __shared__ int prS[64], invS[64], cntTok[64];
  __shared__ int CS[8];
  __shared__ int PsS[8][64], QsS[8][64], aEndS[8][64], eSS[8][64];

  // ---- entry: seq into regs; stage emb (padded) + Wo ----
  const int4 sq = ((const int4*)(seq + b * TT))[tid];   // tokens 4t..4t+3
  const int lastv = seq[b * TT + TT - 1];
  const float4* emb4 = (const float4*)emb;
  for (int i = tid; i < VOC * 64; i += 512) {
    float4 e = emb4[i];
    float* d = &embS[(i >> 6) * EPAD + ((i & 63) << 2)];
    d[0] = e.x; d[1] = e.y; d[2] = e.z; d[3] = e.w;
  }
  {
    const float4* Wo4 = (const float4*)Wo;
    float4* WoS4 = (float4*)WoS;
    for (int i = tid; i < HIDD * VOC / 4; i += 512) WoS4[i] = Wo4[i];
  }
  __syncthreads();

  // ---- gate/dem partial dots: thread = (v, kp in 0..7), 32 k each ----
  {
    const int v = tid & 63, kp = tid >> 6;
    const float* er = &embS[v * EPAD + kp * 32];
    const float* wg = &Wg[kp * 32];
    const float* wd = &Wd[kp * 32];
    float g = 0.f, d = 0.f;
#pragma unroll 8
    for (int k = 0; k < 32; ++k) { float e = er[k]; g += e * wg[k]; d += e * wd[k]; }
    gp8[kp][v] = g; dp8[kp][v] = d;
  }
  __syncthreads();
  if (tid < 64) {
    float g = bg[0], d = bd[0];
#pragma unroll
    for (int p = 0; p < 8; ++p) { g += gp8[p][tid]; d += dp8[p][tid]; }
    int act = (1.f / (1.f + expf(-g)) >= 0.4f) ? 1 : 0;
    demS[tid] = d;
    prS[tid] = act;  // temp: act flag; rank filled next step
  }
  __syncthreads();
  if (tid < 64) {
    float dv = demS[tid];
    int r = 0;
    for (int u2 = 0; u2 < 64; ++u2) {
      float du = demS[u2];
      r += (du < dv || (du == dv && u2 < tid)) ? 1 : 0;
    }
    invS[r] = tid;
    prS[tid] = prS[tid] ? r : 0xFF;
  }
  __syncthreads();

  // ---- pack 4 tokens -> rank bytes; per-wave prefix; scatter to zsB ----
  const int t0 = tid * 4;
  int tk[4] = {sq.x, sq.y, sq.z, sq.w};
  int by[4]; int c = 0;
#pragma unroll
  for (int j = 0; j < 4; ++j) {
    int r = prS[tk[j]];
    by[j] = (t0 + j < TLOOP) ? r : 0xFF;
    c += (by[j] != 0xFF) ? 1 : 0;
  }
  int incl = c;
  for (int s = 1; s < 64; s <<= 1) {
    int t = __shfl_up(incl, s);
    if (lane >= s) incl += t;
  }
  if (lane == 63) CS[wv] = incl;
  __syncthreads();

  int Ow = 0, A = 0;
#pragma unroll
  for (int w2 = 0; w2 < 8; ++w2) {
    int cw = CS[w2];
    Ow += (w2 < wv) ? cw : 0;
    A += cw;
  }
  {
    int pos = Ow + incl - c;
#pragma unroll
    for (int j = 0; j < 4; ++j)
      if (by[j] != 0xFF) zsB[pos++] = (unsigned char)by[j];
  }
  __syncthreads();

  const int fsplit = A < 64 ? A : 64;
  const int nL = A - fsplit;
  const int win = nL < 256 ? nL : 256;
  const int wstart = A - win;
  const int L = (((A + 7) >> 3) + 15) & ~15;  // seg len, mult of 16
  const int baseW = wv * L;
  const int endW = min(baseW + L, A);

  // ---- pass 1: per-segment map (P,Q), lane = rank threshold ----
  int P = 0, Q = NEGBIG;
  for (int g = baseW; g < endW; g += 16) {
    uint4 t4 = *(const uint4*)(zsB + g);
    unsigned dsw[4] = {t4.x, t4.y, t4.z, t4.w};
    const int gHi = min(g + 16, endW);
    if (gHi == g + 16 && gHi <= fsplit) {            // FILL
#pragma unroll
      for (int d = 0; d < 4; ++d)
#pragma unroll
        for (int j = 0; j < 4; ++j) {
          int x = (BYTEAT(dsw[d], j) <= lane) ? 1 : 0;
          P += x; Q += x;
        }
    } else if (gHi == g + 16 && g >= fsplit) {       // LRU
#pragma unroll
      for (int d = 0; d < 4; ++d)
#pragma unroll
        for (int j = 0; j < 4; ++j) {
          int x = (BYTEAT(dsw[d], j) <= lane) ? 1 : 0;
          P += x - 1;
          Q = max(Q + x - 1, x);
        }
    } else {                                         // GATED
#pragma unroll
      for (int d = 0; d < 4; ++d)
#pragma unroll
        for (int j = 0; j < 4; ++j) {
          int i = g + d * 4 + j;
          int x = (BYTEAT(dsw[d], j) <= lane) ? 1 : 0;
          bool vld = i < endW;
          bool fil = i < fsplit;
          int p = fil ? x : x - 1;
          int q = fil ? NEGBIG : x;
          int Pn = P + p;
          int Qn = max(Q + p, q);
          P = vld ? Pn : P;
          Q = vld ? Qn : Q;
        }
    }
  }
  PsS[wv][lane] = P;
  QsS[wv][lane] = Q;
  __syncthreads();

  // ---- combine: entry value for my segment ----
  int a = 0;
  for (int w2 = 0; w2 < wv; ++w2)
    a = max(a + PsS[w2][lane], QsS[w2][lane]);

  // ---- pass 2: rerun segment for final a + windowed eviction count e ----
  int e = 0;
  for (int g = baseW; g < endW; g += 16) {
    uint4 t4 = *(const uint4*)(zsB + g);
    unsigned dsw[4] = {t4.x, t4.y, t4.z, t4.w};
    const int gHi = min(g + 16, endW);
    const bool full = (gHi == g + 16);
    if (full && gHi <= fsplit) {                     // FILL
#pragma unroll
      for (int d = 0; d < 4; ++d)
#pragma unroll
        for (int j = 0; j < 4; ++j)
          a += (BYTEAT(dsw[d], j) <= lane) ? 1 : 0;
    } else if (full && g >= fsplit && gHi <= wstart) {  // MAIN
#pragma unroll
      for (int d = 0; d < 4; ++d)
#pragma unroll
        for (int j = 0; j < 4; ++j) {
          int xm1 = (BYTEAT(dsw[d], j) <= lane) ? 0 : -1;
          a = max(a, 1) + xm1;
        }
    } else if (full && g >= wstart) {                // WIN
#pragma unroll
      for (int d = 0; d < 4; ++d)
#pragma unroll
        for (int j = 0; j < 4; ++j) {
          int xm1 = (BYTEAT(dsw[d], j) <= lane) ? 0 : -1;
          e += (a > 0) ? 1 : 0;
          a = max(a, 1) + xm1;
        }
    } else {                                         // GATED
#pragma unroll
      for (int d = 0; d < 4; ++d)
#pragma unroll
        for (int j = 0; j < 4; ++j) {
          int i = g + d * 4 + j;
          int x = (BYTEAT(dsw[d], j) <= lane) ? 1 : 0;
          bool vld = i < endW;
          bool fil = i < fsplit;
          bool wg = vld && (i >= wstart);
          e += (wg && a > 0) ? 1 : 0;
          int af = a + x;
          int al = max(a, 1) + (x - 1);
          int an = fil ? af : al;
          a = vld ? an : a;
        }
    }
  }
  aEndS[wv][lane] = a;
  eSS[wv][lane] = e;
  __syncthreads();

  // ---- finalize counts (one wave) ----
  if (tid < 64) {
    int af = aEndS[7][lane];
    int et = 0;
#pragma unroll
    for (int w2 = 0; w2 < 8; ++w2) et += eSS[w2][lane];
    int ap = __shfl_up(af, 1); if (lane == 0) ap = 0;
    int ep = __shfl_up(et, 1); if (lane == 0) ep = 0;
    cntTok[invS[lane]] = (af - ap) + (et - ep);
  }

  // ---- qLast = emb[lastv] @ Wq + bq  (512 threads, 2 k-halves) ----
  {
    const int j = tid & 255, half = tid >> 8;
    const float* eL = &embS[lastv * EPAD + half * 128];
    const float* wq = &Wq[(half * 128) * HIDD + j];
    float acc = 0.f;
#pragma unroll 8
    for (int k = 0; k < 128; ++k) acc += eL[k] * wq[k * HIDD];
    qp2[half][j] = acc;
  }
  __syncthreads();
  if (tid < 256) qLastS[tid] = qp2[0][tid] + qp2[1][tid] + bq[tid];
  __syncthreads();

  // ---- scores sc[v] = emb[v].qLast ; softmax regroup over counts ----
  if (tid < 256) {
    int v = tid & 63, part = tid >> 6;
    const float* er = &embS[v * EPAD + part * 64];
    const float* qr = &qLastS[part * 64];
    float s = 0.f;
#pragma unroll 8
    for (int k = 0; k < 64; ++k) s += er[k] * qr[k];
    pp[part][v] = s;
  }
  __syncthreads();
  if (tid < 64) {
    float sc = pp[0][tid] + pp[1][tid] + pp[2][tid] + pp[3][tid];
    int cc = cntTok[tid];
    float m = (cc > 0) ? sc : NEGC;
    for (int off = 32; off; off >>= 1) m = fmaxf(m, __shfl_xor(m, off));
    float w = (cc > 0) ? (float)cc * expf(sc - m) : 0.f;
    float z = w;
    for (int off = 32; off; off >>= 1) z += __shfl_xor(z, off);
    z += (float)(FASTN + SLOWN - (fsplit + win)) * expf(NEGC - m);
    wS[tid] = w / z;
  }
  __syncthreads();

  // ---- ctx[h] = sum_u wS[u] * emb[u][h] ----
  if (tid < 256) {
    float cacc = 0.f;
#pragma unroll 8
    for (int u = 0; u < 64; ++u) cacc += wS[u] * embS[u * EPAD + tid];
    ctxS[tid] = cacc;
  }
  __syncthreads();

  // ---- logits = ctx @ Wo + bo ----
  if (tid < 256) {
    int o = tid & 63, part = tid >> 6;
    const float* cr = &ctxS[part * 64];
    const float* wr = &WoS[part * 64 * VOC + o];
    float s = 0.f;
#pragma unroll 8
    for (int k = 0; k < 64; ++k) s += cr[k] * wr[k * VOC];
    pp[part][o] = s;
  }
  __syncthreads();
  if (tid < 64)
    out[b * VOC + tid] = pp[0][tid] + pp[1][tid] + pp[2][tid] + pp[3][tid] + bo[tid];
  if (tid < 256)
    out[BB * VOC + b * SLOWN + tid] = (tid < win) ? 1.0f : 0.0f;
}

// ---------------------------------------------------------------------------
extern "C" void kernel_launch(void* const* d_in, const int* in_sizes, int n_in,
                              void* d_out, int out_size, void* d_ws, size_t ws_size,
                              hipStream_t stream) {
  const int*   seq = (const int*)d_in[0];
  const float* emb = (const float*)d_in[1];
  const float* Wg  = (const float*)d_in[2];
  const float* bg  = (const float*)d_in[3];
  const float* Wd  = (const float*)d_in[4];
  const float* bd  = (const float*)d_in[5];
  const float* Wq  = (const float*)d_in[6];
  const float* bq  = (const float*)d_in[7];
  const float* Wo  = (const float*)d_in[8];
  const float* bo  = (const float*)d_in[9];
  float* out = (float*)d_out;

  k_one<<<dim3(64), dim3(512), 0, stream>>>(seq, emb, Wg, bg, Wd, bd,
                                            Wq, bq, Wo, bo, out);
}